// Round 7
// baseline (102.261 us; speedup 1.0000x reference)
//
#include <hip/hip_runtime.h>

typedef __attribute__((ext_vector_type(4))) float f32x4;
typedef __attribute__((ext_vector_type(8))) short s16x8;
typedef __attribute__((ext_vector_type(4))) short s16x4;
typedef __attribute__((ext_vector_type(8))) __bf16 bf16x8;

#define B_ 64
#define LQ_ 32
#define LP_ 256
#define H_ 768
#define D_ 128

__device__ __forceinline__ short cvt_bf16(float f) {
  unsigned u = __builtin_bit_cast(unsigned, f);
  unsigned r = (u + 0x7fffu + ((u >> 16) & 1u)) >> 16;
  return (short)r;
}
__device__ __forceinline__ float frombf(short h) {
  unsigned v = ((unsigned)(unsigned short)h) << 16;
  return __builtin_bit_cast(float, v);
}
__device__ __forceinline__ f32x4 mfma16(s16x8 a, s16x8 b, f32x4 c) {
  return __builtin_amdgcn_mfma_f32_16x16x32_bf16(
      __builtin_bit_cast(bf16x8, a), __builtin_bit_cast(bf16x8, b), c, 0, 0, 0);
}
__device__ __forceinline__ s16x8 cvt8(f32x4 a, f32x4 b) {
  s16x8 r;
  r[0] = __builtin_bit_cast(short, (__bf16)a[0]);
  r[1] = __builtin_bit_cast(short, (__bf16)a[1]);
  r[2] = __builtin_bit_cast(short, (__bf16)a[2]);
  r[3] = __builtin_bit_cast(short, (__bf16)a[3]);
  r[4] = __builtin_bit_cast(short, (__bf16)b[0]);
  r[5] = __builtin_bit_cast(short, (__bf16)b[1]);
  r[6] = __builtin_bit_cast(short, (__bf16)b[2]);
  r[7] = __builtin_bit_cast(short, (__bf16)b[3]);
  return r;
}

// ---------------- K1: fused pre-work ----------------
__global__ __launch_bounds__(256) void k_pre(const float* __restrict__ W,
                                             const int* __restrict__ pm,
                                             const int* __restrict__ nm,
                                             short* __restrict__ Wt,
                                             float* __restrict__ mf) {
  __shared__ float tile[32][33];
  int bid = blockIdx.x;
  int t = threadIdx.x;
  if (bid < 96) {
    int k0 = (bid % 24) * 32, n0 = (bid / 24) * 32;
    int r = t >> 3, c4 = (t & 7) << 2;
    f32x4 v = *(const f32x4*)(W + (size_t)(k0 + r) * D_ + n0 + c4);
    tile[r][c4 + 0] = v[0]; tile[r][c4 + 1] = v[1];
    tile[r][c4 + 2] = v[2]; tile[r][c4 + 3] = v[3];
    __syncthreads();
    s16x4 o;
    o[0] = cvt_bf16(tile[c4 + 0][r]);
    o[1] = cvt_bf16(tile[c4 + 1][r]);
    o[2] = cvt_bf16(tile[c4 + 2][r]);
    o[3] = cvt_bf16(tile[c4 + 3][r]);
    *(s16x4*)(Wt + (size_t)(n0 + r) * H_ + k0 + c4) = o;
  } else {
    int i = (bid - 96) * 256 + t;
    float ninf = -__builtin_inff();
    mf[i]         = pm[i] ? 0.f : ninf;
    mf[16384 + i] = nm[i] ? 0.f : ninf;
  }
}

// ---------------- K2: projection GEMM — barrier-free streaming waves ----------------
// 2176 blocks of 1 wave (64 thr). Wave = 32 rows x 64 cols, K=768 in 24 BK=32 chunks.
// A streamed from global through a 4-slot register ring (fully unrolled, static idx);
// B fragments read directly from global (Wt is L2-resident, 192 KB).
__global__ __launch_bounds__(64, 2) void k_proj(
    const float* __restrict__ Hq, const float* __restrict__ Hp, const float* __restrict__ Hn,
    const short* __restrict__ Wt, const float* __restrict__ bias,
    short* __restrict__ Xq, short* __restrict__ Xp, short* __restrict__ Xn,
    float* __restrict__ ps) {
  int bid = blockIdx.x;        // 0..2175
  int strip = bid >> 1;        // 0..1087 (32-row strip, matches ps/k_normfin units)
  int ch = bid & 1;            // column half
  const float* Hs; short* X; int row0;
  if (strip < 64)       { Hs = Hq; X = Xq; row0 = strip * 32; }
  else if (strip < 576) { Hs = Hp; X = Xp; row0 = (strip - 64) * 32; }
  else                  { Hs = Hn; X = Xn; row0 = (strip - 576) * 32; }
  int lane = threadIdx.x;
  int lhi = lane >> 4, llo = lane & 15;

  const float* a0p = Hs + (size_t)(row0 + llo) * H_ + lhi * 8;       // rows 0..15
  const float* a1p = a0p + (size_t)16 * H_;                          // rows 16..31
  const short* bp  = Wt + (size_t)(ch * 64 + llo) * H_ + lhi * 8;    // col group base

  f32x4 aA[4][4];   // [slot][r0lo, r0hi, r1lo, r1hi]
  s16x8 bB[4][4];   // [slot][ni]

#define ISSUE(c)                                                        \
  {                                                                     \
    constexpr int s_ = (c) & 3;                                         \
    constexpr int ko_ = (c) * 32;                                       \
    aA[s_][0] = *(const f32x4*)(a0p + ko_);                             \
    aA[s_][1] = *(const f32x4*)(a0p + ko_ + 4);                         \
    aA[s_][2] = *(const f32x4*)(a1p + ko_);                             \
    aA[s_][3] = *(const f32x4*)(a1p + ko_ + 4);                         \
    bB[s_][0] = *(const s16x8*)(bp + ko_);                              \
    bB[s_][1] = *(const s16x8*)(bp + ko_ + 16 * H_);                    \
    bB[s_][2] = *(const s16x8*)(bp + ko_ + 32 * H_);                    \
    bB[s_][3] = *(const s16x8*)(bp + ko_ + 48 * H_);                    \
  }

  f32x4 acc[2][4] = {};

#define CHUNK(c)                                                        \
  {                                                                     \
    constexpr int s_ = (c) & 3;                                         \
    s16x8 af0 = cvt8(aA[s_][0], aA[s_][1]);                             \
    s16x8 af1 = cvt8(aA[s_][2], aA[s_][3]);                             \
    acc[0][0] = mfma16(af0, bB[s_][0], acc[0][0]);                      \
    acc[0][1] = mfma16(af0, bB[s_][1], acc[0][1]);                      \
    acc[0][2] = mfma16(af0, bB[s_][2], acc[0][2]);                      \
    acc[0][3] = mfma16(af0, bB[s_][3], acc[0][3]);                      \
    acc[1][0] = mfma16(af1, bB[s_][0], acc[1][0]);                      \
    acc[1][1] = mfma16(af1, bB[s_][1], acc[1][1]);                      \
    acc[1][2] = mfma16(af1, bB[s_][2], acc[1][2]);                      \
    acc[1][3] = mfma16(af1, bB[s_][3], acc[1][3]);                      \
    if ((c) + 4 < 24) ISSUE((c) + 4)                                    \
    __builtin_amdgcn_sched_barrier(0);                                  \
  }

  ISSUE(0) ISSUE(1) ISSUE(2) ISSUE(3)
  __builtin_amdgcn_sched_barrier(0);
  CHUNK(0)  CHUNK(1)  CHUNK(2)  CHUNK(3)  CHUNK(4)  CHUNK(5)
  CHUNK(6)  CHUNK(7)  CHUNK(8)  CHUNK(9)  CHUNK(10) CHUNK(11)
  CHUNK(12) CHUNK(13) CHUNK(14) CHUNK(15) CHUNK(16) CHUNK(17)
  CHUNK(18) CHUNK(19) CHUNK(20) CHUNK(21) CHUNK(22) CHUNK(23)
#undef CHUNK
#undef ISSUE

  // epilogue: bias, bf16 X write, 32-row column sumsq partial into ps[strip]
  for (int ni = 0; ni < 4; ni++) {
    int col = ch * 64 + ni * 16 + llo;
    float bv = bias[col];
    float s = 0.f;
    for (int mi = 0; mi < 2; mi++) {
      for (int r = 0; r < 4; r++) {
        float xv = acc[mi][ni][r] + bv;
        s += xv * xv;
        X[(size_t)(row0 + mi * 16 + lhi * 4 + r) * D_ + col] = cvt_bf16(xv);
      }
    }
    s += __shfl_xor(s, 16, 64);
    s += __shfl_xor(s, 32, 64);
    if (lhi == 0) ps[(size_t)strip * 128 + col] = s;
  }
}

// ---------------- K3: finalize norm + write bf16 V ----------------
// 1088 blocks of 32 rows; ps in 32-row units (1088 x 128), unit == bid.
__global__ __launch_bounds__(256) void k_normfin(
    const short* __restrict__ Xq, const short* __restrict__ Xp, const short* __restrict__ Xn,
    const float* __restrict__ ps,
    short* __restrict__ Vq, short* __restrict__ Vp, short* __restrict__ Vn) {
  __shared__ float invs[128];
  int bid = blockIdx.x;
  const short* X; short* V; int row0, pbase, pcnt;
  if (bid < 64)       { X = Xq; V = Vq; row0 = bid * 32;         pbase = bid;                        pcnt = 1; }
  else if (bid < 576) { X = Xp; V = Vp; row0 = (bid - 64) * 32;  pbase = 64 + ((bid - 64) & ~7);     pcnt = 8; }
  else                { X = Xn; V = Vn; row0 = (bid - 576) * 32; pbase = 576 + ((bid - 576) & ~7);   pcnt = 8; }
  int t = threadIdx.x;
  if (t < 128) {
    float s = 0.f;
    for (int j = 0; j < pcnt; j++) s += ps[(size_t)(pbase + j) * 128 + t];
    invs[t] = 1.0f / fmaxf(sqrtf(s), 1e-12f);
  }
  __syncthreads();
  int row = row0 + (t >> 3), c0 = (t & 7) << 4;
  const short* xr = X + (size_t)row * D_ + c0;
  s16x8 x0 = *(const s16x8*)(xr);
  s16x8 x1 = *(const s16x8*)(xr + 8);
  f32x4 i0 = *(const f32x4*)(&invs[c0]);
  f32x4 i1 = *(const f32x4*)(&invs[c0 + 4]);
  f32x4 i2 = *(const f32x4*)(&invs[c0 + 8]);
  f32x4 i3 = *(const f32x4*)(&invs[c0 + 12]);
  s16x8 o0, o1;
  for (int j = 0; j < 4; j++) {
    o0[j]     = cvt_bf16(frombf(x0[j])     * i0[j]);
    o0[j + 4] = cvt_bf16(frombf(x0[j + 4]) * i1[j]);
    o1[j]     = cvt_bf16(frombf(x1[j])     * i2[j]);
    o1[j + 4] = cvt_bf16(frombf(x1[j + 4]) * i3[j]);
  }
  short* vr = V + (size_t)row * D_ + c0;
  *(s16x8*)(vr) = o0;
  *(s16x8*)(vr + 8) = o1;
}

// ---------------- K4: MaxSim, swapped operands (P=A in LDS, Q=B in regs) ----------------
__global__ __launch_bounds__(512, 2) void k_maxsim(
    const short* __restrict__ QV, const short* __restrict__ PV, const short* __restrict__ NV,
    const float* __restrict__ MF, float* __restrict__ OUT) {
  __shared__ short Ps[LP_ * D_];  // 64 KB, XOR-swizzled (pitch 256 B)
  int t = threadIdx.x, lane = t & 63, w = t >> 6;
  int lhi = lane >> 4, llo = lane & 15;
  int c = blockIdx.x, side = blockIdx.y, quarter = blockIdx.z;
  const short* P = side ? NV : PV;
  const float* mfb = MF + (size_t)(side * B_ + c) * LP_;

  const short* qb = QV + (size_t)(quarter * 512 + w * 64) * D_;
  s16x8 bq[4][4];
  for (int ni = 0; ni < 4; ni++)
    for (int ks = 0; ks < 4; ks++)
      bq[ni][ks] = *(const s16x8*)(qb + (size_t)(ni * 16 + llo) * D_ + ks * 32 + lhi * 8);

  const short* src = P + (size_t)c * LP_ * D_;
  for (int i = 0; i < 8; i++) {
    int s = i * 512 + t;
    int p = s >> 4, kc = s & 15;
    s16x8 v = *(const s16x8*)(src + (size_t)p * D_ + kc * 8);
    int byteoff = (p * 256 + kc * 16) ^ ((p & 7) << 4);
    *(s16x8*)((char*)Ps + byteoff) = v;
  }
  __syncthreads();

  float ninf = -__builtin_inff();
  float rmax[4] = {ninf, ninf, ninf, ninf};
  for (int pi = 0; pi < 4; pi++) {
    f32x4 acc[4][4] = {};  // [mi][ni]
    for (int ks = 0; ks < 4; ks++) {
      s16x8 pa[4];
      for (int mi = 0; mi < 4; mi++) {
        int prow = pi * 64 + mi * 16 + llo;
        int off = (prow * 256 + ks * 64 + lhi * 16) ^ ((prow & 7) << 4);
        pa[mi] = *(const s16x8*)((char*)Ps + off);
      }
      __builtin_amdgcn_s_setprio(1);
      for (int mi = 0; mi < 4; mi++)
        for (int ni = 0; ni < 4; ni++)
          acc[mi][ni] = mfma16(pa[mi], bq[ni][ks], acc[mi][ni]);
      __builtin_amdgcn_s_setprio(0);
    }
    f32x4 mk[4];
    for (int mi = 0; mi < 4; mi++)
      mk[mi] = *(const f32x4*)(mfb + pi * 64 + mi * 16 + lhi * 4);
    for (int ni = 0; ni < 4; ni++)
      for (int mi = 0; mi < 4; mi++)
        for (int r = 0; r < 4; r++)
          rmax[ni] = fmaxf(rmax[ni], acc[mi][ni][r] + mk[mi][r]);
  }
  for (int ni = 0; ni < 4; ni++) {
    rmax[ni] = fmaxf(rmax[ni], __shfl_xor(rmax[ni], 16, 64));
    rmax[ni] = fmaxf(rmax[ni], __shfl_xor(rmax[ni], 32, 64));
  }
  float s0 = rmax[0] + rmax[1];
  float s1 = rmax[2] + rmax[3];
  for (int m = 1; m < 16; m <<= 1) {
    s0 += __shfl_xor(s0, m, 64);
    s1 += __shfl_xor(s1, m, 64);
  }
  if (lane == 0) {
    int b0 = quarter * 16 + w * 2;
    OUT[(size_t)b0 * 128 + side * 64 + c] = s0;
    OUT[(size_t)(b0 + 1) * 128 + side * 64 + c] = s1;
  }
}

extern "C" void kernel_launch(void* const* d_in, const int* in_sizes, int n_in,
                              void* d_out, int out_size, void* d_ws, size_t ws_size,
                              hipStream_t stream) {
  const float* qh = (const float*)d_in[0];
  const float* ph = (const float*)d_in[1];
  const float* nh = (const float*)d_in[2];
  const float* W  = (const float*)d_in[3];
  const float* bias = (const float*)d_in[4];
  const int* pm = (const int*)d_in[5];
  const int* nm = (const int*)d_in[6];
  float* out = (float*)d_out;
  char* ws = (char*)d_ws;

  short* Wt = (short*)(ws + 0x0);        // 128x768 bf16      192 KB
  float* mf = (float*)(ws + 0x30000);    // 2x64x256 f32      128 KB
  float* ps = (float*)(ws + 0x50000);    // 1088x128 f32      557 KB
  short* xq = (short*)(ws + 0x160000);   // 2048x128 bf16     512 KB
  short* xp = (short*)(ws + 0x1E0000);   // 16384x128 bf16    4 MB
  short* xn = (short*)(ws + 0x5E0000);   // 16384x128 bf16    4 MB
  short* qv = (short*)(ws + 0x9E0000);   // 2048x128 bf16     512 KB
  short* pv = (short*)(ws + 0xA60000);   // 16384x128 bf16    4 MB
  short* nv = (short*)(ws + 0xE60000);   // 16384x128 bf16    4 MB

  k_pre<<<160, 256, 0, stream>>>(W, pm, nm, Wt, mf);
  k_proj<<<2176, 64, 0, stream>>>(qh, ph, nh, Wt, bias, xq, xp, xn, ps);
  k_normfin<<<1088, 256, 0, stream>>>(xq, xp, xn, ps, qv, pv, nv);
  k_maxsim<<<dim3(64, 2, 4), 512, 0, stream>>>(qv, pv, nv, mf, out);
}

// Round 8
// 85.244 us; speedup vs baseline: 1.1996x; 1.1996x over previous
//
#include <hip/hip_runtime.h>

typedef __attribute__((ext_vector_type(4))) float f32x4;
typedef __attribute__((ext_vector_type(8))) short s16x8;
typedef __attribute__((ext_vector_type(4))) short s16x4;
typedef __attribute__((ext_vector_type(8))) __bf16 bf16x8;

#define B_ 64
#define LQ_ 32
#define LP_ 256
#define H_ 768
#define D_ 128

__device__ __forceinline__ short cvt_bf16(float f) {
  unsigned u = __builtin_bit_cast(unsigned, f);
  unsigned r = (u + 0x7fffu + ((u >> 16) & 1u)) >> 16;
  return (short)r;
}
__device__ __forceinline__ float frombf(short h) {
  unsigned v = ((unsigned)(unsigned short)h) << 16;
  return __builtin_bit_cast(float, v);
}
__device__ __forceinline__ f32x4 mfma16(s16x8 a, s16x8 b, f32x4 c) {
  return __builtin_amdgcn_mfma_f32_16x16x32_bf16(
      __builtin_bit_cast(bf16x8, a), __builtin_bit_cast(bf16x8, b), c, 0, 0, 0);
}
__device__ __forceinline__ s16x8 cvt8(f32x4 a, f32x4 b) {
  s16x8 r;
  r[0] = __builtin_bit_cast(short, (__bf16)a[0]);
  r[1] = __builtin_bit_cast(short, (__bf16)a[1]);
  r[2] = __builtin_bit_cast(short, (__bf16)a[2]);
  r[3] = __builtin_bit_cast(short, (__bf16)a[3]);
  r[4] = __builtin_bit_cast(short, (__bf16)b[0]);
  r[5] = __builtin_bit_cast(short, (__bf16)b[1]);
  r[6] = __builtin_bit_cast(short, (__bf16)b[2]);
  r[7] = __builtin_bit_cast(short, (__bf16)b[3]);
  return r;
}

// ---------------- K1: fused pre-work ----------------
__global__ __launch_bounds__(256) void k_pre(const float* __restrict__ W,
                                             const int* __restrict__ pm,
                                             const int* __restrict__ nm,
                                             short* __restrict__ Wt,
                                             float* __restrict__ mf) {
  __shared__ float tile[32][33];
  int bid = blockIdx.x;
  int t = threadIdx.x;
  if (bid < 96) {
    int k0 = (bid % 24) * 32, n0 = (bid / 24) * 32;
    int r = t >> 3, c4 = (t & 7) << 2;
    f32x4 v = *(const f32x4*)(W + (size_t)(k0 + r) * D_ + n0 + c4);
    tile[r][c4 + 0] = v[0]; tile[r][c4 + 1] = v[1];
    tile[r][c4 + 2] = v[2]; tile[r][c4 + 3] = v[3];
    __syncthreads();
    s16x4 o;
    o[0] = cvt_bf16(tile[c4 + 0][r]);
    o[1] = cvt_bf16(tile[c4 + 1][r]);
    o[2] = cvt_bf16(tile[c4 + 2][r]);
    o[3] = cvt_bf16(tile[c4 + 3][r]);
    *(s16x4*)(Wt + (size_t)(n0 + r) * H_ + k0 + c4) = o;
  } else {
    int i = (bid - 96) * 256 + t;
    float ninf = -__builtin_inff();
    mf[i]         = pm[i] ? 0.f : ninf;
    mf[16384 + i] = nm[i] ? 0.f : ninf;
  }
}

// ---------------- K2: projection GEMM — B-stationary in LDS, stream A ----------------
// grid (272 rowgroups, 2 col-halves), 512 thr (8 waves). Block stages its 64-col half
// of Wt (96 KB, XOR-swizzled) ONCE; then each wave independently streams a 16-row
// strip (24 BK=32 chunks) with a 2-slot A register pipeline. No steady-state barriers.
__global__ __launch_bounds__(512, 2) void k_proj(
    const float* __restrict__ Hq, const float* __restrict__ Hp, const float* __restrict__ Hn,
    const short* __restrict__ Wt, const float* __restrict__ bias,
    short* __restrict__ Xq, short* __restrict__ Xp, short* __restrict__ Xn,
    float* __restrict__ ps) {
  __shared__ __attribute__((aligned(128))) char Bs[64 * 1536];  // 96 KB
  int g = blockIdx.x, ch = blockIdx.y;
  const float* Hs; short* X; int grow0;
  if (g < 16)       { Hs = Hq; X = Xq; grow0 = g * 128; }
  else if (g < 144) { Hs = Hp; X = Xp; grow0 = (g - 16) * 128; }
  else              { Hs = Hn; X = Xn; grow0 = (g - 144) * 128; }
  int t = threadIdx.x, lane = t & 63, w = t >> 6;
  int lhi = lane >> 4, llo = lane & 15;

  // ---- stage B half: Wt rows [ch*64, ch*64+64), swizzle byte ^= ((row&7)<<4) ----
  {
    const char* wb = (const char*)(Wt + (size_t)ch * 64 * H_);
    for (int i = 0; i < 12; i++) {
      int gid = i * 512 + t;        // 16-B granule id, 6144 total
      int row = gid / 96;
      int ob = (gid - row * 96) * 16;
      s16x8 v = *(const s16x8*)(wb + row * 1536 + ob);
      *(s16x8*)(Bs + row * 1536 + (ob ^ ((row & 7) << 4))) = v;
    }
  }
  __syncthreads();

  // ---- wave-private 16-row strip ----
  int row0 = grow0 + w * 16;
  const float* a0p = Hs + (size_t)(row0 + llo) * H_ + lhi * 8;

  // B frag addressing: frag(ni, it) at br*1536 + ((it^cx)*64) + ((lhi*16)^((br&3)<<4))
  int brbase[4], cx;
  cx = (llo >> 2) & 1;
  for (int ni = 0; ni < 4; ni++) {
    int br = ni * 16 + llo;
    brbase[ni] = br * 1536 + ((lhi * 16) ^ ((br & 3) << 4));
  }

  f32x4 A0a = *(const f32x4*)(a0p);
  f32x4 A0b = *(const f32x4*)(a0p + 4);
  f32x4 A1a = *(const f32x4*)(a0p + 32);
  f32x4 A1b = *(const f32x4*)(a0p + 36);

  f32x4 acc[4] = {};

#define STEP(IT, SLOT)                                                      \
  {                                                                         \
    s16x8 af = (SLOT == 0) ? cvt8(A0a, A0b) : cvt8(A1a, A1b);               \
    if ((IT) + 2 < 24) {                                                    \
      if (SLOT == 0) {                                                      \
        A0a = *(const f32x4*)(a0p + ((IT) + 2) * 32);                       \
        A0b = *(const f32x4*)(a0p + ((IT) + 2) * 32 + 4);                   \
      } else {                                                              \
        A1a = *(const f32x4*)(a0p + ((IT) + 2) * 32);                       \
        A1b = *(const f32x4*)(a0p + ((IT) + 2) * 32 + 4);                   \
      }                                                                     \
    }                                                                       \
    s16x8 b0 = *(const s16x8*)(Bs + brbase[0] + (((IT) ^ cx) << 6));        \
    s16x8 b1 = *(const s16x8*)(Bs + brbase[1] + (((IT) ^ cx) << 6));        \
    s16x8 b2 = *(const s16x8*)(Bs + brbase[2] + (((IT) ^ cx) << 6));        \
    s16x8 b3 = *(const s16x8*)(Bs + brbase[3] + (((IT) ^ cx) << 6));        \
    acc[0] = mfma16(af, b0, acc[0]);                                        \
    acc[1] = mfma16(af, b1, acc[1]);                                        \
    acc[2] = mfma16(af, b2, acc[2]);                                        \
    acc[3] = mfma16(af, b3, acc[3]);                                        \
  }

  STEP(0, 0)  STEP(1, 1)  STEP(2, 0)  STEP(3, 1)
  STEP(4, 0)  STEP(5, 1)  STEP(6, 0)  STEP(7, 1)
  STEP(8, 0)  STEP(9, 1)  STEP(10, 0) STEP(11, 1)
  STEP(12, 0) STEP(13, 1) STEP(14, 0) STEP(15, 1)
  STEP(16, 0) STEP(17, 1) STEP(18, 0) STEP(19, 1)
  STEP(20, 0) STEP(21, 1) STEP(22, 0) STEP(23, 1)
#undef STEP

  // epilogue: bias, bf16 X write, 16-row column sumsq -> ps[unit = g*8+w]
  for (int ni = 0; ni < 4; ni++) {
    int col = ch * 64 + ni * 16 + llo;
    float bv = bias[col];
    float s = 0.f;
    for (int r = 0; r < 4; r++) {
      float xv = acc[ni][r] + bv;
      s += xv * xv;
      X[(size_t)(row0 + lhi * 4 + r) * D_ + col] = cvt_bf16(xv);
    }
    s += __shfl_xor(s, 16, 64);
    s += __shfl_xor(s, 32, 64);
    if (lhi == 0) ps[(size_t)(g * 8 + w) * 128 + col] = s;
  }
}

// ---------------- K3: finalize norm + write bf16 V ----------------
// 1088 blocks of 32 rows; ps in 16-row units (2176 x 128).
__global__ __launch_bounds__(256) void k_normfin(
    const short* __restrict__ Xq, const short* __restrict__ Xp, const short* __restrict__ Xn,
    const float* __restrict__ ps,
    short* __restrict__ Vq, short* __restrict__ Vp, short* __restrict__ Vn) {
  __shared__ float invs[128];
  int bid = blockIdx.x;
  const short* X; short* V; int row0, pbase, pcnt;
  if (bid < 64)       { X = Xq; V = Vq; row0 = bid * 32;         pbase = bid * 2;                       pcnt = 2;  }
  else if (bid < 576) { X = Xp; V = Vp; row0 = (bid - 64) * 32;  pbase = 128 + ((bid - 64) / 8) * 16;   pcnt = 16; }
  else                { X = Xn; V = Vn; row0 = (bid - 576) * 32; pbase = 1152 + ((bid - 576) / 8) * 16; pcnt = 16; }
  int t = threadIdx.x;
  if (t < 128) {
    float s = 0.f;
    for (int j = 0; j < pcnt; j++) s += ps[(size_t)(pbase + j) * 128 + t];
    invs[t] = 1.0f / fmaxf(sqrtf(s), 1e-12f);
  }
  __syncthreads();
  int row = row0 + (t >> 3), c0 = (t & 7) << 4;
  const short* xr = X + (size_t)row * D_ + c0;
  s16x8 x0 = *(const s16x8*)(xr);
  s16x8 x1 = *(const s16x8*)(xr + 8);
  f32x4 i0 = *(const f32x4*)(&invs[c0]);
  f32x4 i1 = *(const f32x4*)(&invs[c0 + 4]);
  f32x4 i2 = *(const f32x4*)(&invs[c0 + 8]);
  f32x4 i3 = *(const f32x4*)(&invs[c0 + 12]);
  s16x8 o0, o1;
  for (int j = 0; j < 4; j++) {
    o0[j]     = cvt_bf16(frombf(x0[j])     * i0[j]);
    o0[j + 4] = cvt_bf16(frombf(x0[j + 4]) * i1[j]);
    o1[j]     = cvt_bf16(frombf(x1[j])     * i2[j]);
    o1[j + 4] = cvt_bf16(frombf(x1[j + 4]) * i3[j]);
  }
  short* vr = V + (size_t)row * D_ + c0;
  *(s16x8*)(vr) = o0;
  *(s16x8*)(vr + 8) = o1;
}

// ---------------- K4: MaxSim, swapped operands (P=A in LDS, Q=B in regs) ----------------
__global__ __launch_bounds__(512, 2) void k_maxsim(
    const short* __restrict__ QV, const short* __restrict__ PV, const short* __restrict__ NV,
    const float* __restrict__ MF, float* __restrict__ OUT) {
  __shared__ short Ps[LP_ * D_];  // 64 KB, XOR-swizzled (pitch 256 B)
  int t = threadIdx.x, lane = t & 63, w = t >> 6;
  int lhi = lane >> 4, llo = lane & 15;
  int c = blockIdx.x, side = blockIdx.y, quarter = blockIdx.z;
  const short* P = side ? NV : PV;
  const float* mfb = MF + (size_t)(side * B_ + c) * LP_;

  const short* qb = QV + (size_t)(quarter * 512 + w * 64) * D_;
  s16x8 bq[4][4];
  for (int ni = 0; ni < 4; ni++)
    for (int ks = 0; ks < 4; ks++)
      bq[ni][ks] = *(const s16x8*)(qb + (size_t)(ni * 16 + llo) * D_ + ks * 32 + lhi * 8);

  const short* src = P + (size_t)c * LP_ * D_;
  for (int i = 0; i < 8; i++) {
    int s = i * 512 + t;
    int p = s >> 4, kc = s & 15;
    s16x8 v = *(const s16x8*)(src + (size_t)p * D_ + kc * 8);
    int byteoff = (p * 256 + kc * 16) ^ ((p & 7) << 4);
    *(s16x8*)((char*)Ps + byteoff) = v;
  }
  __syncthreads();

  float ninf = -__builtin_inff();
  float rmax[4] = {ninf, ninf, ninf, ninf};
  for (int pi = 0; pi < 4; pi++) {
    f32x4 acc[4][4] = {};  // [mi][ni]
    for (int ks = 0; ks < 4; ks++) {
      s16x8 pa[4];
      for (int mi = 0; mi < 4; mi++) {
        int prow = pi * 64 + mi * 16 + llo;
        int off = (prow * 256 + ks * 64 + lhi * 16) ^ ((prow & 7) << 4);
        pa[mi] = *(const s16x8*)((char*)Ps + off);
      }
      __builtin_amdgcn_s_setprio(1);
      for (int mi = 0; mi < 4; mi++)
        for (int ni = 0; ni < 4; ni++)
          acc[mi][ni] = mfma16(pa[mi], bq[ni][ks], acc[mi][ni]);
      __builtin_amdgcn_s_setprio(0);
    }
    f32x4 mk[4];
    for (int mi = 0; mi < 4; mi++)
      mk[mi] = *(const f32x4*)(mfb + pi * 64 + mi * 16 + lhi * 4);
    for (int ni = 0; ni < 4; ni++)
      for (int mi = 0; mi < 4; mi++)
        for (int r = 0; r < 4; r++)
          rmax[ni] = fmaxf(rmax[ni], acc[mi][ni][r] + mk[mi][r]);
  }
  for (int ni = 0; ni < 4; ni++) {
    rmax[ni] = fmaxf(rmax[ni], __shfl_xor(rmax[ni], 16, 64));
    rmax[ni] = fmaxf(rmax[ni], __shfl_xor(rmax[ni], 32, 64));
  }
  float s0 = rmax[0] + rmax[1];
  float s1 = rmax[2] + rmax[3];
  for (int m = 1; m < 16; m <<= 1) {
    s0 += __shfl_xor(s0, m, 64);
    s1 += __shfl_xor(s1, m, 64);
  }
  if (lane == 0) {
    int b0 = quarter * 16 + w * 2;
    OUT[(size_t)b0 * 128 + side * 64 + c] = s0;
    OUT[(size_t)(b0 + 1) * 128 + side * 64 + c] = s1;
  }
}

extern "C" void kernel_launch(void* const* d_in, const int* in_sizes, int n_in,
                              void* d_out, int out_size, void* d_ws, size_t ws_size,
                              hipStream_t stream) {
  const float* qh = (const float*)d_in[0];
  const float* ph = (const float*)d_in[1];
  const float* nh = (const float*)d_in[2];
  const float* W  = (const float*)d_in[3];
  const float* bias = (const float*)d_in[4];
  const int* pm = (const int*)d_in[5];
  const int* nm = (const int*)d_in[6];
  float* out = (float*)d_out;
  char* ws = (char*)d_ws;

  short* Wt = (short*)(ws + 0x0);        // 128x768 bf16      192 KB
  float* mf = (float*)(ws + 0x30000);    // 2x64x256 f32      128 KB
  float* ps = (float*)(ws + 0x50000);    // 2176x128 f32      1.11 MB
  short* xq = (short*)(ws + 0x160000);   // 2048x128 bf16     512 KB
  short* xp = (short*)(ws + 0x1E0000);   // 16384x128 bf16    4 MB
  short* xn = (short*)(ws + 0x5E0000);   // 16384x128 bf16    4 MB
  short* qv = (short*)(ws + 0x9E0000);   // 2048x128 bf16     512 KB
  short* pv = (short*)(ws + 0xA60000);   // 16384x128 bf16    4 MB
  short* nv = (short*)(ws + 0xE60000);   // 16384x128 bf16    4 MB

  k_pre<<<160, 256, 0, stream>>>(W, pm, nm, Wt, mf);
  k_proj<<<dim3(272, 2), 512, 0, stream>>>(qh, ph, nh, Wt, bias, xq, xp, xn, ps);
  k_normfin<<<1088, 256, 0, stream>>>(xq, xp, xn, ps, qv, pv, nv);
  k_maxsim<<<dim3(64, 2, 4), 512, 0, stream>>>(qv, pv, nv, mf, out);
}